// Round 1
// baseline (806.999 us; speedup 1.0000x reference)
//
#include <hip/hip_runtime.h>
#include <hip/hip_bf16.h>

typedef __attribute__((ext_vector_type(8))) short short8;
typedef __attribute__((ext_vector_type(4))) float floatx4;

static __device__ inline unsigned short f2bf(float f) {
    unsigned u = __float_as_uint(f);
    unsigned r = (u + 0x7fffu + ((u >> 16) & 1u)) >> 16;
    return (unsigned short)r;
}

// ---------------- Fused layer1+layer2: h2 = silu(LN(silu(LN(xe@W1+b1))@W2+b2)) ----------
// Outputs h2 as bf16 [E,128] (consumed only by the MFMA gemm3).
__global__ __launch_bounds__(256) void mlp12_kernel(
    const float* __restrict__ xe,
    const float* __restrict__ W1, const float* __restrict__ b1,
    const float* __restrict__ g1, const float* __restrict__ be1,
    const float* __restrict__ W2, const float* __restrict__ b2,
    const float* __restrict__ g2, const float* __restrict__ be2,
    unsigned short* __restrict__ h2b, int E)
{
    __shared__ float As[64 * 132];
    __shared__ float Bs[16 * 128];
    __shared__ float redS[64 * 16];
    __shared__ float redQ[64 * 16];
    __shared__ float mrow[64];
    __shared__ float rrow[64];

    int t  = threadIdx.x;
    int tx = t & 15;        // output-col group (8 cols each)
    int ty = t >> 4;        // row group (4 rows each)
    int e0 = blockIdx.x * 64;

    for (int idx = t; idx < 64 * 32; idx += 256) {
        int row = idx >> 5;
        int c4  = (idx & 31) * 4;
        float4 v = make_float4(0.f, 0.f, 0.f, 0.f);
        if (e0 + row < E) v = *(const float4*)(xe + (size_t)(e0 + row) * 128 + c4);
        *(float4*)&As[row * 132 + c4] = v;
    }

    const float* Wl = W1; const float* bl = b1; const float* gl = g1; const float* bel = be1;
    float acc[4][8];

    for (int layer = 0; layer < 2; layer++) {
        for (int r = 0; r < 4; r++)
            for (int i = 0; i < 8; i++) acc[r][i] = 0.f;

        for (int kk = 0; kk < 128; kk += 16) {
            __syncthreads();
            for (int idx = t; idx < 16 * 32; idx += 256) {
                int row = idx >> 5;
                int c4  = (idx & 31) * 4;
                *(float4*)&Bs[row * 128 + c4] = *(const float4*)(Wl + (size_t)(kk + row) * 128 + c4);
            }
            __syncthreads();
            // 4 k's per step: A read is one ds_read_b128 per row instead of 4 scalars.
            for (int k4 = 0; k4 < 16; k4 += 4) {
                float b[4][8];
                #pragma unroll
                for (int kb = 0; kb < 4; kb++) {
                    float4 bv0 = *(float4*)&Bs[(k4 + kb) * 128 + tx * 8];
                    float4 bv1 = *(float4*)&Bs[(k4 + kb) * 128 + tx * 8 + 4];
                    b[kb][0] = bv0.x; b[kb][1] = bv0.y; b[kb][2] = bv0.z; b[kb][3] = bv0.w;
                    b[kb][4] = bv1.x; b[kb][5] = bv1.y; b[kb][6] = bv1.z; b[kb][7] = bv1.w;
                }
                #pragma unroll
                for (int r = 0; r < 4; r++) {
                    float4 a4 = *(float4*)&As[(ty * 4 + r) * 132 + kk + k4];
                    #pragma unroll
                    for (int i = 0; i < 8; i++)
                        acc[r][i] += a4.x * b[0][i] + a4.y * b[1][i]
                                   + a4.z * b[2][i] + a4.w * b[3][i];
                }
            }
        }

        float gg[8], bebe[8];
        for (int i = 0; i < 8; i++) {
            float bb = bl[tx * 8 + i];
            gg[i]    = gl[tx * 8 + i];
            bebe[i]  = bel[tx * 8 + i];
            for (int r = 0; r < 4; r++) acc[r][i] += bb;
        }
        for (int r = 0; r < 4; r++) {
            float s = 0.f, q = 0.f;
            for (int i = 0; i < 8; i++) { s += acc[r][i]; q += acc[r][i] * acc[r][i]; }
            redS[(ty * 4 + r) * 16 + tx] = s;
            redQ[(ty * 4 + r) * 16 + tx] = q;
        }
        __syncthreads();
        if (t < 64) {
            float s = 0.f, q = 0.f;
            for (int i = 0; i < 16; i++) { s += redS[t * 16 + i]; q += redQ[t * 16 + i]; }
            float mu  = s * (1.f / 128.f);
            float var = q * (1.f / 128.f) - mu * mu;
            mrow[t] = mu;
            rrow[t] = rsqrtf(var + 1e-6f);
        }
        __syncthreads();
        for (int r = 0; r < 4; r++) {
            int e_loc = ty * 4 + r;
            float mu = mrow[e_loc], rs = rrow[e_loc];
            for (int i = 0; i < 8; i++) {
                float v = (acc[r][i] - mu) * rs * gg[i] + bebe[i];
                acc[r][i] = v / (1.f + __expf(-v));   // silu
            }
        }
        if (layer == 0) {
            for (int r = 0; r < 4; r++) {
                int e_loc = ty * 4 + r;
                for (int i = 0; i < 8; i++) As[e_loc * 132 + tx * 8 + i] = acc[r][i];
            }
            __syncthreads();
            Wl = W2; bl = b2; gl = g2; bel = be2;
        } else {
            for (int r = 0; r < 4; r++) {
                int e = e0 + ty * 4 + r;
                if (e < E) {
                    unsigned p[4];
                    for (int i = 0; i < 4; i++)
                        p[i] = (unsigned)f2bf(acc[r][2 * i]) | ((unsigned)f2bf(acc[r][2 * i + 1]) << 16);
                    *(uint4*)(h2b + (size_t)e * 128 + tx * 8) = make_uint4(p[0], p[1], p[2], p[3]);
                }
            }
        }
    }
}

// ---------------- W3 transpose prep: W3bT[n][k] = bf16(W3[k][n]), [640][128] ------------
__global__ __launch_bounds__(256) void w3t_kernel(const float* __restrict__ W3,
                                                  unsigned short* __restrict__ W3bT)
{
    int idx = blockIdx.x * 256 + threadIdx.x;   // 81920 total
    int n = idx >> 7, k = idx & 127;
    W3bT[idx] = f2bf(W3[(size_t)k * 640 + n]);
}

// ---------------- Layer 3 via MFMA: h3 = h2 @ W3 + b3, stored bf16 [E,640] --------------
// Block tile 64(M)x128(N), K=128. 4 waves in 2x2; wave tile 32x64.
// B fragments live in registers, loaded straight from L2-resident W3bT.
// Operands SWAPPED in the mfma call -> output arrives transposed: lane holds 4
// consecutive n for a fixed row m, enabling packed 8B stores (16 rows x 32B per inst).
__global__ __launch_bounds__(256) void gemm3_mfma_kernel(
    const unsigned short* __restrict__ h2b, const unsigned short* __restrict__ W3bT,
    const float* __restrict__ b3, unsigned short* __restrict__ h3b, int E)
{
    __shared__ unsigned short As[64 * 136];   // +8 bf16 pad: row stride 68 dwords -> 2-way max

    int t    = threadIdx.x;
    int lane = t & 63;
    int w    = t >> 6;
    int mw   = w & 1, nw = w >> 1;
    int l15  = lane & 15, quad = lane >> 4;
    int e0   = blockIdx.x * 64;
    int n0   = blockIdx.y * 128;

    // stage A tile (64 x 128 bf16) to LDS
    for (int p = 0; p < 4; p++) {
        int idx = p * 256 + t;              // 1024 16B-chunks
        int row = idx >> 4;
        int c16 = idx & 15;
        uint4 v = make_uint4(0, 0, 0, 0);
        if (e0 + row < E) v = *(const uint4*)(h2b + (size_t)(e0 + row) * 128 + c16 * 8);
        *(uint4*)&As[row * 136 + c16 * 8] = v;
    }

    // B fragments: [kstep][nf], each lane: B[k=ks*32+quad*8+j][n=n_base+nf*16+l15]
    short8 bfrag[4][4];
    {
        const unsigned short* bbase = W3bT + (size_t)(n0 + nw * 64) * 128;
        for (int ks = 0; ks < 4; ks++)
            for (int nf = 0; nf < 4; nf++)
                bfrag[ks][nf] = *(const short8*)(bbase + (size_t)(nf * 16 + l15) * 128 + ks * 32 + quad * 8);
    }

    floatx4 acc[2][4];
    for (int mf = 0; mf < 2; mf++)
        for (int nf = 0; nf < 4; nf++)
            acc[mf][nf] = (floatx4){0.f, 0.f, 0.f, 0.f};

    __syncthreads();

    for (int ks = 0; ks < 4; ks++) {
        short8 afrag[2];
        for (int mf = 0; mf < 2; mf++)
            afrag[mf] = *(const short8*)&As[(mw * 32 + mf * 16 + l15) * 136 + ks * 32 + quad * 8];
        // swapped operands: D = (h2 @ W3)^T tile; row index = n, col index (lane&15) = m
        for (int mf = 0; mf < 2; mf++)
            for (int nf = 0; nf < 4; nf++)
                acc[mf][nf] = __builtin_amdgcn_mfma_f32_16x16x32_bf16(
                    bfrag[ks][nf], afrag[mf], acc[mf][nf], 0, 0, 0);
    }

    // epilogue (transposed layout): lane (quad,l15) holds, for each (mf,nf),
    // rows m = e0+mw*32+mf*16+l15, cols n = n0+nw*64+nf*16+quad*4 + r (r=0..3).
    for (int nf = 0; nf < 4; nf++) {
        float4 bias = *(const float4*)&b3[n0 + nw * 64 + nf * 16 + quad * 4];
        for (int mf = 0; mf < 2; mf++) {
            int m = e0 + mw * 32 + mf * 16 + l15;
            if (m < E) {
                floatx4 v = acc[mf][nf];
                unsigned lo = (unsigned)f2bf(v[0] + bias.x) | ((unsigned)f2bf(v[1] + bias.y) << 16);
                unsigned hi = (unsigned)f2bf(v[2] + bias.z) | ((unsigned)f2bf(v[3] + bias.w) << 16);
                *(uint2*)(h3b + (size_t)m * 640 + n0 + nw * 64 + nf * 16 + quad * 4) = make_uint2(lo, hi);
            }
        }
    }
}

// ---------------- CSR build ---------------------------------------------------------
__global__ void hist_kernel(const int* __restrict__ ei, const int* __restrict__ noff,
                            int* __restrict__ counts, int E)
{
    int i = blockIdx.x * blockDim.x + threadIdx.x;
    if (i < E) {
        int tgt = ei[E + i] - noff[0];
        atomicAdd(&counts[tgt], 1);
    }
}

__global__ __launch_bounds__(1024) void scan_kernel(const int* __restrict__ counts,
                                                    int* __restrict__ offsets,
                                                    int* __restrict__ cursor, int N)
{
    __shared__ int part[1024];
    int t = threadIdx.x;
    int per = (N + 1023) / 1024;
    int beg = t * per;
    int end = beg + per; if (end > N) end = N; if (beg > N) beg = N;
    int s = 0;
    for (int i = beg; i < end; i++) s += counts[i];
    part[t] = s;
    __syncthreads();
    for (int off = 1; off < 1024; off <<= 1) {
        int v = part[t];
        int u = (t >= off) ? part[t - off] : 0;
        __syncthreads();
        part[t] = v + u;
        __syncthreads();
    }
    int run = (t == 0) ? 0 : part[t - 1];
    for (int i = beg; i < end; i++) {
        offsets[i] = run;
        cursor[i]  = run;
        run += counts[i];
    }
    if (t == 1023) offsets[N] = part[1023];
}

__global__ void scatter_kernel(const int* __restrict__ ei, const int* __restrict__ noff,
                               int* __restrict__ cursor, int* __restrict__ edge_ids, int E)
{
    int i = blockIdx.x * blockDim.x + threadIdx.x;
    if (i < E) {
        int tgt = ei[E + i] - noff[0];
        int pos = atomicAdd(&cursor[tgt], 1);
        edge_ids[pos] = i;
    }
}

// ---------------- Gather: out[n] = x[n] + (1/16) * sum_e env_e * wig_e[:, :5] @ h3_e ----
// T14 async-STAGE split + double buffer: next edge's global loads are issued into
// registers BEFORE computing the current edge from LDS; LDS writes land after, into
// the alternate buffer; one barrier per edge.
__global__ __launch_bounds__(256) void gather_kernel(
    const float* __restrict__ x, const unsigned short* __restrict__ h3b,
    const float* __restrict__ wig, const float* __restrict__ env,
    const int* __restrict__ offsets, const int* __restrict__ edge_ids,
    float* __restrict__ out, int N)
{
    __shared__ float sw[2][25 * 8];   // padded wigner rows [j][k], k<5
    __shared__ float sh[2][640];      // h3 row as fp32 [k][c]
    __shared__ float sev[2];
    int n = blockIdx.x;
    int t = threadIdx.x;
    int c = t & 127;
    int half = t >> 7;             // 0: even j, 1: odd j
    int njj = half ? 12 : 13;
    float acc[13];
    for (int i = 0; i < 13; i++) acc[i] = 0.f;

    int beg = offsets[n], end = offsets[n + 1];
    int wj = t / 5, wk = t - wj * 5;   // for t<125

    if (beg < end) {
        int e = edge_ids[beg];
        float wv = 0.f;
        if (t < 125) wv = wig[(size_t)e * 475 + wj * 19 + wk];
        const unsigned* hp = (const unsigned*)(h3b + (size_t)e * 640);
        unsigned h0 = hp[t];
        unsigned h1 = (t < 64) ? hp[256 + t] : 0u;
        float evv = (t == 0) ? env[e] : 0.f;
        if (t < 125) sw[0][wj * 8 + wk] = wv;
        sh[0][2 * t]     = __uint_as_float(h0 << 16);
        sh[0][2 * t + 1] = __uint_as_float(h0 & 0xffff0000u);
        if (t < 64) {
            sh[0][2 * (256 + t)]     = __uint_as_float(h1 << 16);
            sh[0][2 * (256 + t) + 1] = __uint_as_float(h1 & 0xffff0000u);
        }
        if (t == 0) sev[0] = evv;
    }
    __syncthreads();

    for (int ii = beg; ii < end; ii++) {
        int buf = (ii - beg) & 1;
        int nb  = buf ^ 1;
        bool has_next = (ii + 1 < end);
        float wv = 0.f, evv = 0.f;
        unsigned h0 = 0u, h1 = 0u;
        if (has_next) {
            int e_nxt = edge_ids[ii + 1];
            if (t < 125) wv = wig[(size_t)e_nxt * 475 + wj * 19 + wk];
            const unsigned* hp = (const unsigned*)(h3b + (size_t)e_nxt * 640);
            h0 = hp[t];
            if (t < 64) h1 = hp[256 + t];
            if (t == 0) evv = env[e_nxt];
        }

        // compute current edge from LDS buffer `buf`
        float ev  = sev[buf];
        float hv0 = sh[buf][c],       hv1 = sh[buf][128 + c], hv2 = sh[buf][256 + c],
              hv3 = sh[buf][384 + c], hv4 = sh[buf][512 + c];
        for (int jj = 0; jj < njj; jj++) {
            int j = half + jj * 2;
            float4 w4 = *(float4*)&sw[buf][j * 8];
            float we  = sw[buf][j * 8 + 4];
            float d = w4.x * hv0 + w4.y * hv1 + w4.z * hv2 + w4.w * hv3 + we * hv4;
            acc[jj] += ev * d;
        }

        // write next edge into alternate buffer (loads have been in flight)
        if (has_next) {
            if (t < 125) sw[nb][wj * 8 + wk] = wv;
            sh[nb][2 * t]     = __uint_as_float(h0 << 16);
            sh[nb][2 * t + 1] = __uint_as_float(h0 & 0xffff0000u);
            if (t < 64) {
                sh[nb][2 * (256 + t)]     = __uint_as_float(h1 << 16);
                sh[nb][2 * (256 + t) + 1] = __uint_as_float(h1 & 0xffff0000u);
            }
            if (t == 0) sev[nb] = evv;
        }
        __syncthreads();
    }

    size_t base = (size_t)n * 3200;
    for (int jj = 0; jj < njj; jj++) {
        int j = half + jj * 2;
        out[base + j * 128 + c] = x[base + j * 128 + c] + acc[jj] * 0.0625f;
    }
}

extern "C" void kernel_launch(void* const* d_in, const int* in_sizes, int n_in,
                              void* d_out, int out_size, void* d_ws, size_t ws_size,
                              hipStream_t stream) {
    const float* x          = (const float*)d_in[0];
    const float* x_edge     = (const float*)d_in[1];
    const int*   edge_index = (const int*)d_in[2];
    const float* wigner     = (const float*)d_in[3];
    const float* envel      = (const float*)d_in[4];
    const int*   node_off   = (const int*)d_in[5];
    const float* W1 = (const float*)d_in[6];
    const float* b1 = (const float*)d_in[7];
    const float* g1 = (const float*)d_in[8];
    const float* be1 = (const float*)d_in[9];
    const float* W2 = (const float*)d_in[10];
    const float* b2 = (const float*)d_in[11];
    const float* g2 = (const float*)d_in[12];
    const float* be2 = (const float*)d_in[13];
    const float* W3 = (const float*)d_in[14];
    const float* b3 = (const float*)d_in[15];
    float* out = (float*)d_out;

    int E = in_sizes[1] / 128;    // 100000
    int N = in_sizes[0] / 3200;   // 6250

    // workspace layout
    char* w = (char*)d_ws;
    unsigned short* h2b  = (unsigned short*)w; w += (size_t)E * 128 * sizeof(unsigned short);
    unsigned short* h3b  = (unsigned short*)w; w += (size_t)E * 640 * sizeof(unsigned short);
    unsigned short* W3bT = (unsigned short*)w; w += (size_t)640 * 128 * sizeof(unsigned short);
    int* counts   = (int*)w;            w += (size_t)((N + 63) & ~63) * sizeof(int);
    int* offsets  = (int*)w;            w += (size_t)((N + 1 + 63) & ~63) * sizeof(int);
    int* cursor   = (int*)w;            w += (size_t)((N + 63) & ~63) * sizeof(int);
    int* edge_ids = (int*)w;            w += (size_t)E * sizeof(int);

    hipMemsetAsync(counts, 0, (size_t)N * sizeof(int), stream);

    dim3 blk(256);
    mlp12_kernel<<<dim3((E + 63) / 64), blk, 0, stream>>>(
        x_edge, W1, b1, g1, be1, W2, b2, g2, be2, h2b, E);

    w3t_kernel<<<dim3(320), blk, 0, stream>>>(W3, W3bT);

    hist_kernel<<<dim3((E + 255) / 256), blk, 0, stream>>>(edge_index, node_off, counts, E);
    scan_kernel<<<dim3(1), dim3(1024), 0, stream>>>(counts, offsets, cursor, N);
    scatter_kernel<<<dim3((E + 255) / 256), blk, 0, stream>>>(edge_index, node_off, cursor, edge_ids, E);

    gemm3_mfma_kernel<<<dim3((E + 63) / 64, 5), blk, 0, stream>>>(h2b, W3bT, b3, h3b, E);

    gather_kernel<<<dim3(N), blk, 0, stream>>>(x, h3b, wigner, envel, offsets, edge_ids, out, N);
}

// Round 2
// 701.143 us; speedup vs baseline: 1.1510x; 1.1510x over previous
//
#include <hip/hip_runtime.h>
#include <hip/hip_bf16.h>

typedef __attribute__((ext_vector_type(8))) short short8;
typedef __attribute__((ext_vector_type(4))) float floatx4;

static __device__ inline unsigned short f2bf(float f) {
    unsigned u = __float_as_uint(f);
    unsigned r = (u + 0x7fffu + ((u >> 16) & 1u)) >> 16;
    return (unsigned short)r;
}

// split fp32 into truncated-hi bf16 + rounded-lo bf16 (x ~= hi + lo, err ~2^-17 rel)
static __device__ inline void split_bf(float f, unsigned short& hi, unsigned short& lo) {
    unsigned u = __float_as_uint(f);
    hi = (unsigned short)(u >> 16);
    float hf = __uint_as_float(u & 0xffff0000u);
    lo = f2bf(f - hf);
}

// ---------------- W1/W2 transpose+split prep: W?h/W?l[n][k] bf16, [128][128] ------------
__global__ __launch_bounds__(256) void w12t_kernel(
    const float* __restrict__ W1, const float* __restrict__ W2,
    unsigned short* __restrict__ W1h, unsigned short* __restrict__ W1l,
    unsigned short* __restrict__ W2h, unsigned short* __restrict__ W2l)
{
    int idx = blockIdx.x * 256 + threadIdx.x;   // 32768 total
    int which = idx >> 14;
    int r = idx & 16383;
    int n = r >> 7, k = r & 127;
    const float* W = which ? W2 : W1;
    float f = W[(size_t)k * 128 + n];
    unsigned short hi, lo;
    split_bf(f, hi, lo);
    if (which) { W2h[r] = hi; W2l[r] = lo; }
    else       { W1h[r] = hi; W1l[r] = lo; }
}

// ---------------- Fused layer1+layer2 via MFMA (hi/lo bf16 split ~ fp32 precision) ------
// Block = 256 thr (4 waves), 64 edge rows; wave w owns rows w*16..w*16+15.
// Swapped-operand mfma_16x16x32: lane (quad,l15) holds row l15, cols nf*16+quad*4+r.
// LN reduce = 2x shfl_xor (lanes l15, l15+16, l15+32, l15+48). No LDS for stats.
__global__ __launch_bounds__(256) void mlp12_kernel(
    const float* __restrict__ xe,
    const unsigned short* __restrict__ W1h, const unsigned short* __restrict__ W1l,
    const float* __restrict__ b1, const float* __restrict__ g1, const float* __restrict__ be1,
    const unsigned short* __restrict__ W2h, const unsigned short* __restrict__ W2l,
    const float* __restrict__ b2, const float* __restrict__ g2, const float* __restrict__ be2,
    unsigned short* __restrict__ h2b, int E)
{
    __shared__ unsigned short Ah[64 * 136];   // h1 hi, row stride 136 (2-way max conflicts)
    __shared__ unsigned short Al[64 * 136];   // h1 lo

    int t    = threadIdx.x;
    int lane = t & 63;
    int w    = t >> 6;
    int l15  = lane & 15, quad = lane >> 4;
    int row_loc = w * 16 + l15;               // 0..63
    size_t e = (size_t)blockIdx.x * 64 + row_loc;
    bool rowok = (e < (size_t)E);

    floatx4 acc[8];

    #pragma unroll
    for (int layer = 0; layer < 2; layer++) {
        const unsigned short* Wh  = layer ? W2h : W1h;
        const unsigned short* Wlo = layer ? W2l : W1l;
        #pragma unroll
        for (int nf = 0; nf < 8; nf++) acc[nf] = (floatx4){0.f, 0.f, 0.f, 0.f};

        #pragma unroll
        for (int ks = 0; ks < 4; ks++) {
            short8 ah, al;
            if (layer == 0) {
                float f[8] = {0.f,0.f,0.f,0.f,0.f,0.f,0.f,0.f};
                if (rowok) {
                    float4 v0 = *(const float4*)(xe + e * 128 + ks * 32 + quad * 8);
                    float4 v1 = *(const float4*)(xe + e * 128 + ks * 32 + quad * 8 + 4);
                    f[0] = v0.x; f[1] = v0.y; f[2] = v0.z; f[3] = v0.w;
                    f[4] = v1.x; f[5] = v1.y; f[6] = v1.z; f[7] = v1.w;
                }
                #pragma unroll
                for (int j = 0; j < 8; j++) {
                    unsigned short h, l;
                    split_bf(f[j], h, l);
                    ah[j] = (short)h; al[j] = (short)l;
                }
            } else {
                ah = *(const short8*)&Ah[row_loc * 136 + ks * 32 + quad * 8];
                al = *(const short8*)&Al[row_loc * 136 + ks * 32 + quad * 8];
            }
            #pragma unroll
            for (int nf = 0; nf < 8; nf++) {
                size_t wo = (size_t)(nf * 16 + l15) * 128 + ks * 32 + quad * 8;
                short8 wh = *(const short8*)(Wh  + wo);
                short8 wl = *(const short8*)(Wlo + wo);
                acc[nf] = __builtin_amdgcn_mfma_f32_16x16x32_bf16(wh, ah, acc[nf], 0, 0, 0);
                acc[nf] = __builtin_amdgcn_mfma_f32_16x16x32_bf16(wh, al, acc[nf], 0, 0, 0);
                acc[nf] = __builtin_amdgcn_mfma_f32_16x16x32_bf16(wl, ah, acc[nf], 0, 0, 0);
            }
        }

        const float* bl  = layer ? b2  : b1;
        const float* gl  = layer ? g2  : g1;
        const float* bel = layer ? be2 : be1;

        // bias + LN stats (per-lane partial over 32 cols, then 4-lane shfl reduce)
        float s = 0.f, q = 0.f;
        #pragma unroll
        for (int nf = 0; nf < 8; nf++) {
            float4 bb = *(const float4*)(bl + nf * 16 + quad * 4);
            acc[nf][0] += bb.x; acc[nf][1] += bb.y; acc[nf][2] += bb.z; acc[nf][3] += bb.w;
            #pragma unroll
            for (int r = 0; r < 4; r++) { s += acc[nf][r]; q += acc[nf][r] * acc[nf][r]; }
        }
        s += __shfl_xor(s, 16); s += __shfl_xor(s, 32);
        q += __shfl_xor(q, 16); q += __shfl_xor(q, 32);
        float mu  = s * (1.f / 128.f);
        float var = q * (1.f / 128.f) - mu * mu;
        float rs  = rsqrtf(var + 1e-6f);

        if (layer == 0) {
            #pragma unroll
            for (int nf = 0; nf < 8; nf++) {
                float4 gg  = *(const float4*)(gl  + nf * 16 + quad * 4);
                float4 bb2 = *(const float4*)(bel + nf * 16 + quad * 4);
                float vv[4];
                vv[0] = (acc[nf][0] - mu) * rs * gg.x + bb2.x;
                vv[1] = (acc[nf][1] - mu) * rs * gg.y + bb2.y;
                vv[2] = (acc[nf][2] - mu) * rs * gg.z + bb2.z;
                vv[3] = (acc[nf][3] - mu) * rs * gg.w + bb2.w;
                unsigned short h4[4], l4[4];
                #pragma unroll
                for (int r = 0; r < 4; r++) {
                    float v = vv[r];
                    v = v / (1.f + __expf(-v));       // silu
                    split_bf(v, h4[r], l4[r]);
                }
                *(uint2*)&Ah[row_loc * 136 + nf * 16 + quad * 4] =
                    make_uint2((unsigned)h4[0] | ((unsigned)h4[1] << 16),
                               (unsigned)h4[2] | ((unsigned)h4[3] << 16));
                *(uint2*)&Al[row_loc * 136 + nf * 16 + quad * 4] =
                    make_uint2((unsigned)l4[0] | ((unsigned)l4[1] << 16),
                               (unsigned)l4[2] | ((unsigned)l4[3] << 16));
            }
            __syncthreads();
        } else {
            if (rowok) {
                #pragma unroll
                for (int nf = 0; nf < 8; nf++) {
                    float4 gg  = *(const float4*)(gl  + nf * 16 + quad * 4);
                    float4 bb2 = *(const float4*)(bel + nf * 16 + quad * 4);
                    unsigned short p[4];
                    float vv[4];
                    vv[0] = (acc[nf][0] - mu) * rs * gg.x + bb2.x;
                    vv[1] = (acc[nf][1] - mu) * rs * gg.y + bb2.y;
                    vv[2] = (acc[nf][2] - mu) * rs * gg.z + bb2.z;
                    vv[3] = (acc[nf][3] - mu) * rs * gg.w + bb2.w;
                    #pragma unroll
                    for (int r = 0; r < 4; r++) {
                        float v = vv[r];
                        v = v / (1.f + __expf(-v));   // silu
                        p[r] = f2bf(v);
                    }
                    *(uint2*)(h2b + e * 128 + nf * 16 + quad * 4) =
                        make_uint2((unsigned)p[0] | ((unsigned)p[1] << 16),
                                   (unsigned)p[2] | ((unsigned)p[3] << 16));
                }
            }
        }
    }
}

// ---------------- W3 transpose prep: W3bT[n][k] = bf16(W3[k][n]), [640][128] ------------
__global__ __launch_bounds__(256) void w3t_kernel(const float* __restrict__ W3,
                                                  unsigned short* __restrict__ W3bT)
{
    int idx = blockIdx.x * 256 + threadIdx.x;   // 81920 total
    int n = idx >> 7, k = idx & 127;
    W3bT[idx] = f2bf(W3[(size_t)k * 640 + n]);
}

// ---------------- Layer 3 via MFMA: h3 = h2 @ W3 + b3, stored bf16 [E,640] --------------
// Block tile 64(M)x128(N), K=128. 4 waves in 2x2; wave tile 32x64.
// B fragments live in registers, loaded straight from L2-resident W3bT.
// Operands SWAPPED in the mfma call -> output arrives transposed: lane holds 4
// consecutive n for a fixed row m, enabling packed 8B stores (16 rows x 32B per inst).
__global__ __launch_bounds__(256) void gemm3_mfma_kernel(
    const unsigned short* __restrict__ h2b, const unsigned short* __restrict__ W3bT,
    const float* __restrict__ b3, unsigned short* __restrict__ h3b, int E)
{
    __shared__ unsigned short As[64 * 136];   // +8 bf16 pad: row stride 68 dwords -> 2-way max

    int t    = threadIdx.x;
    int lane = t & 63;
    int w    = t >> 6;
    int mw   = w & 1, nw = w >> 1;
    int l15  = lane & 15, quad = lane >> 4;
    int e0   = blockIdx.x * 64;
    int n0   = blockIdx.y * 128;

    // stage A tile (64 x 128 bf16) to LDS
    for (int p = 0; p < 4; p++) {
        int idx = p * 256 + t;              // 1024 16B-chunks
        int row = idx >> 4;
        int c16 = idx & 15;
        uint4 v = make_uint4(0, 0, 0, 0);
        if (e0 + row < E) v = *(const uint4*)(h2b + (size_t)(e0 + row) * 128 + c16 * 8);
        *(uint4*)&As[row * 136 + c16 * 8] = v;
    }

    // B fragments: [kstep][nf], each lane: B[k=ks*32+quad*8+j][n=n_base+nf*16+l15]
    short8 bfrag[4][4];
    {
        const unsigned short* bbase = W3bT + (size_t)(n0 + nw * 64) * 128;
        for (int ks = 0; ks < 4; ks++)
            for (int nf = 0; nf < 4; nf++)
                bfrag[ks][nf] = *(const short8*)(bbase + (size_t)(nf * 16 + l15) * 128 + ks * 32 + quad * 8);
    }

    floatx4 acc[2][4];
    for (int mf = 0; mf < 2; mf++)
        for (int nf = 0; nf < 4; nf++)
            acc[mf][nf] = (floatx4){0.f, 0.f, 0.f, 0.f};

    __syncthreads();

    for (int ks = 0; ks < 4; ks++) {
        short8 afrag[2];
        for (int mf = 0; mf < 2; mf++)
            afrag[mf] = *(const short8*)&As[(mw * 32 + mf * 16 + l15) * 136 + ks * 32 + quad * 8];
        // swapped operands: D = (h2 @ W3)^T tile; row index = n, col index (lane&15) = m
        for (int mf = 0; mf < 2; mf++)
            for (int nf = 0; nf < 4; nf++)
                acc[mf][nf] = __builtin_amdgcn_mfma_f32_16x16x32_bf16(
                    bfrag[ks][nf], afrag[mf], acc[mf][nf], 0, 0, 0);
    }

    // epilogue (transposed layout): lane (quad,l15) holds, for each (mf,nf),
    // rows m = e0+mw*32+mf*16+l15, cols n = n0+nw*64+nf*16+quad*4 + r (r=0..3).
    for (int nf = 0; nf < 4; nf++) {
        float4 bias = *(const float4*)&b3[n0 + nw * 64 + nf * 16 + quad * 4];
        for (int mf = 0; mf < 2; mf++) {
            int m = e0 + mw * 32 + mf * 16 + l15;
            if (m < E) {
                floatx4 v = acc[mf][nf];
                unsigned lo = (unsigned)f2bf(v[0] + bias.x) | ((unsigned)f2bf(v[1] + bias.y) << 16);
                unsigned hi = (unsigned)f2bf(v[2] + bias.z) | ((unsigned)f2bf(v[3] + bias.w) << 16);
                *(uint2*)(h3b + (size_t)m * 640 + n0 + nw * 64 + nf * 16 + quad * 4) = make_uint2(lo, hi);
            }
        }
    }
}

// ---------------- CSR build ---------------------------------------------------------
__global__ void hist_kernel(const int* __restrict__ ei, const int* __restrict__ noff,
                            int* __restrict__ counts, int E)
{
    int i = blockIdx.x * blockDim.x + threadIdx.x;
    if (i < E) {
        int tgt = ei[E + i] - noff[0];
        atomicAdd(&counts[tgt], 1);
    }
}

__global__ __launch_bounds__(1024) void scan_kernel(const int* __restrict__ counts,
                                                    int* __restrict__ offsets,
                                                    int* __restrict__ cursor, int N)
{
    __shared__ int part[1024];
    int t = threadIdx.x;
    int per = (N + 1023) / 1024;
    int beg = t * per;
    int end = beg + per; if (end > N) end = N; if (beg > N) beg = N;
    int s = 0;
    for (int i = beg; i < end; i++) s += counts[i];
    part[t] = s;
    __syncthreads();
    for (int off = 1; off < 1024; off <<= 1) {
        int v = part[t];
        int u = (t >= off) ? part[t - off] : 0;
        __syncthreads();
        part[t] = v + u;
        __syncthreads();
    }
    int run = (t == 0) ? 0 : part[t - 1];
    for (int i = beg; i < end; i++) {
        offsets[i] = run;
        cursor[i]  = run;
        run += counts[i];
    }
    if (t == 1023) offsets[N] = part[1023];
}

__global__ void scatter_kernel(const int* __restrict__ ei, const int* __restrict__ noff,
                               int* __restrict__ cursor, int* __restrict__ edge_ids, int E)
{
    int i = blockIdx.x * blockDim.x + threadIdx.x;
    if (i < E) {
        int tgt = ei[E + i] - noff[0];
        int pos = atomicAdd(&cursor[tgt], 1);
        edge_ids[pos] = i;
    }
}

// ---------------- Gather: out[n] = x[n] + (1/16) * sum_e env_e * wig_e[:, :5] @ h3_e ----
// T14 async-STAGE split + double buffer: next edge's global loads are issued into
// registers BEFORE computing the current edge from LDS; LDS writes land after, into
// the alternate buffer; one barrier per edge.
__global__ __launch_bounds__(256) void gather_kernel(
    const float* __restrict__ x, const unsigned short* __restrict__ h3b,
    const float* __restrict__ wig, const float* __restrict__ env,
    const int* __restrict__ offsets, const int* __restrict__ edge_ids,
    float* __restrict__ out, int N)
{
    __shared__ float sw[2][25 * 8];   // padded wigner rows [j][k], k<5
    __shared__ float sh[2][640];      // h3 row as fp32 [k][c]
    __shared__ float sev[2];
    int n = blockIdx.x;
    int t = threadIdx.x;
    int c = t & 127;
    int half = t >> 7;             // 0: even j, 1: odd j
    int njj = half ? 12 : 13;
    float acc[13];
    for (int i = 0; i < 13; i++) acc[i] = 0.f;

    int beg = offsets[n], end = offsets[n + 1];
    int wj = t / 5, wk = t - wj * 5;   // for t<125

    if (beg < end) {
        int e = edge_ids[beg];
        float wv = 0.f;
        if (t < 125) wv = wig[(size_t)e * 475 + wj * 19 + wk];
        const unsigned* hp = (const unsigned*)(h3b + (size_t)e * 640);
        unsigned h0 = hp[t];
        unsigned h1 = (t < 64) ? hp[256 + t] : 0u;
        float evv = (t == 0) ? env[e] : 0.f;
        if (t < 125) sw[0][wj * 8 + wk] = wv;
        sh[0][2 * t]     = __uint_as_float(h0 << 16);
        sh[0][2 * t + 1] = __uint_as_float(h0 & 0xffff0000u);
        if (t < 64) {
            sh[0][2 * (256 + t)]     = __uint_as_float(h1 << 16);
            sh[0][2 * (256 + t) + 1] = __uint_as_float(h1 & 0xffff0000u);
        }
        if (t == 0) sev[0] = evv;
    }
    __syncthreads();

    for (int ii = beg; ii < end; ii++) {
        int buf = (ii - beg) & 1;
        int nb  = buf ^ 1;
        bool has_next = (ii + 1 < end);
        float wv = 0.f, evv = 0.f;
        unsigned h0 = 0u, h1 = 0u;
        if (has_next) {
            int e_nxt = edge_ids[ii + 1];
            if (t < 125) wv = wig[(size_t)e_nxt * 475 + wj * 19 + wk];
            const unsigned* hp = (const unsigned*)(h3b + (size_t)e_nxt * 640);
            h0 = hp[t];
            if (t < 64) h1 = hp[256 + t];
            if (t == 0) evv = env[e_nxt];
        }

        // compute current edge from LDS buffer `buf`
        float ev  = sev[buf];
        float hv0 = sh[buf][c],       hv1 = sh[buf][128 + c], hv2 = sh[buf][256 + c],
              hv3 = sh[buf][384 + c], hv4 = sh[buf][512 + c];
        for (int jj = 0; jj < njj; jj++) {
            int j = half + jj * 2;
            float4 w4 = *(float4*)&sw[buf][j * 8];
            float we  = sw[buf][j * 8 + 4];
            float d = w4.x * hv0 + w4.y * hv1 + w4.z * hv2 + w4.w * hv3 + we * hv4;
            acc[jj] += ev * d;
        }

        // write next edge into alternate buffer (loads have been in flight)
        if (has_next) {
            if (t < 125) sw[nb][wj * 8 + wk] = wv;
            sh[nb][2 * t]     = __uint_as_float(h0 << 16);
            sh[nb][2 * t + 1] = __uint_as_float(h0 & 0xffff0000u);
            if (t < 64) {
                sh[nb][2 * (256 + t)]     = __uint_as_float(h1 << 16);
                sh[nb][2 * (256 + t) + 1] = __uint_as_float(h1 & 0xffff0000u);
            }
            if (t == 0) sev[nb] = evv;
        }
        __syncthreads();
    }

    size_t base = (size_t)n * 3200;
    for (int jj = 0; jj < njj; jj++) {
        int j = half + jj * 2;
        out[base + j * 128 + c] = x[base + j * 128 + c] + acc[jj] * 0.0625f;
    }
}

extern "C" void kernel_launch(void* const* d_in, const int* in_sizes, int n_in,
                              void* d_out, int out_size, void* d_ws, size_t ws_size,
                              hipStream_t stream) {
    const float* x          = (const float*)d_in[0];
    const float* x_edge     = (const float*)d_in[1];
    const int*   edge_index = (const int*)d_in[2];
    const float* wigner     = (const float*)d_in[3];
    const float* envel      = (const float*)d_in[4];
    const int*   node_off   = (const int*)d_in[5];
    const float* W1 = (const float*)d_in[6];
    const float* b1 = (const float*)d_in[7];
    const float* g1 = (const float*)d_in[8];
    const float* be1 = (const float*)d_in[9];
    const float* W2 = (const float*)d_in[10];
    const float* b2 = (const float*)d_in[11];
    const float* g2 = (const float*)d_in[12];
    const float* be2 = (const float*)d_in[13];
    const float* W3 = (const float*)d_in[14];
    const float* b3 = (const float*)d_in[15];
    float* out = (float*)d_out;

    int E = in_sizes[1] / 128;    // 100000
    int N = in_sizes[0] / 3200;   // 6250

    // workspace layout
    char* w = (char*)d_ws;
    unsigned short* h2b  = (unsigned short*)w; w += (size_t)E * 128 * sizeof(unsigned short);
    unsigned short* h3b  = (unsigned short*)w; w += (size_t)E * 640 * sizeof(unsigned short);
    unsigned short* W3bT = (unsigned short*)w; w += (size_t)640 * 128 * sizeof(unsigned short);
    unsigned short* W1h  = (unsigned short*)w; w += (size_t)128 * 128 * sizeof(unsigned short);
    unsigned short* W1l  = (unsigned short*)w; w += (size_t)128 * 128 * sizeof(unsigned short);
    unsigned short* W2h  = (unsigned short*)w; w += (size_t)128 * 128 * sizeof(unsigned short);
    unsigned short* W2l  = (unsigned short*)w; w += (size_t)128 * 128 * sizeof(unsigned short);
    int* counts   = (int*)w;            w += (size_t)((N + 63) & ~63) * sizeof(int);
    int* offsets  = (int*)w;            w += (size_t)((N + 1 + 63) & ~63) * sizeof(int);
    int* cursor   = (int*)w;            w += (size_t)((N + 63) & ~63) * sizeof(int);
    int* edge_ids = (int*)w;            w += (size_t)E * sizeof(int);

    hipMemsetAsync(counts, 0, (size_t)N * sizeof(int), stream);

    dim3 blk(256);
    w12t_kernel<<<dim3(128), blk, 0, stream>>>(W1, W2, W1h, W1l, W2h, W2l);

    mlp12_kernel<<<dim3((E + 63) / 64), blk, 0, stream>>>(
        x_edge, W1h, W1l, b1, g1, be1, W2h, W2l, b2, g2, be2, h2b, E);

    w3t_kernel<<<dim3(320), blk, 0, stream>>>(W3, W3bT);

    hist_kernel<<<dim3((E + 255) / 256), blk, 0, stream>>>(edge_index, node_off, counts, E);
    scan_kernel<<<dim3(1), dim3(1024), 0, stream>>>(counts, offsets, cursor, N);
    scatter_kernel<<<dim3((E + 255) / 256), blk, 0, stream>>>(edge_index, node_off, cursor, edge_ids, E);

    gemm3_mfma_kernel<<<dim3((E + 63) / 64, 5), blk, 0, stream>>>(h2b, W3bT, b3, h3b, E);

    gather_kernel<<<dim3(N), blk, 0, stream>>>(x, h3b, wigner, envel, offsets, edge_ids, out, N);
}

// Round 3
// 694.561 us; speedup vs baseline: 1.1619x; 1.0095x over previous
//
#include <hip/hip_runtime.h>
#include <hip/hip_bf16.h>

typedef __attribute__((ext_vector_type(8))) short short8;
typedef __attribute__((ext_vector_type(4))) float floatx4;

static __device__ inline unsigned short f2bf(float f) {
    unsigned u = __float_as_uint(f);
    unsigned r = (u + 0x7fffu + ((u >> 16) & 1u)) >> 16;
    return (unsigned short)r;
}

// split fp32 into truncated-hi bf16 + rounded-lo bf16 (x ~= hi + lo, err ~2^-17 rel)
static __device__ inline void split_bf(float f, unsigned short& hi, unsigned short& lo) {
    unsigned u = __float_as_uint(f);
    hi = (unsigned short)(u >> 16);
    float hf = __uint_as_float(u & 0xffff0000u);
    lo = f2bf(f - hf);
}

// ---------------- W1/W2 transpose+split prep: W?h/W?l[n][k] bf16, [128][128] ------------
__global__ __launch_bounds__(256) void w12t_kernel(
    const float* __restrict__ W1, const float* __restrict__ W2,
    unsigned short* __restrict__ W1h, unsigned short* __restrict__ W1l,
    unsigned short* __restrict__ W2h, unsigned short* __restrict__ W2l)
{
    int idx = blockIdx.x * 256 + threadIdx.x;   // 32768 total
    int which = idx >> 14;
    int r = idx & 16383;
    int n = r >> 7, k = r & 127;
    const float* W = which ? W2 : W1;
    float f = W[(size_t)k * 128 + n];
    unsigned short hi, lo;
    split_bf(f, hi, lo);
    if (which) { W2h[r] = hi; W2l[r] = lo; }
    else       { W1h[r] = hi; W1l[r] = lo; }
}

// ---------------- Fused layer1+layer2 via MFMA (hi/lo bf16 split ~ fp32 precision) ------
__global__ __launch_bounds__(256) void mlp12_kernel(
    const float* __restrict__ xe,
    const unsigned short* __restrict__ W1h, const unsigned short* __restrict__ W1l,
    const float* __restrict__ b1, const float* __restrict__ g1, const float* __restrict__ be1,
    const unsigned short* __restrict__ W2h, const unsigned short* __restrict__ W2l,
    const float* __restrict__ b2, const float* __restrict__ g2, const float* __restrict__ be2,
    unsigned short* __restrict__ h2b, int E)
{
    __shared__ unsigned short Ah[64 * 136];   // h1 hi, row stride 136 (2-way max conflicts)
    __shared__ unsigned short Al[64 * 136];   // h1 lo

    int t    = threadIdx.x;
    int lane = t & 63;
    int w    = t >> 6;
    int l15  = lane & 15, quad = lane >> 4;
    int row_loc = w * 16 + l15;               // 0..63
    size_t e = (size_t)blockIdx.x * 64 + row_loc;
    bool rowok = (e < (size_t)E);

    floatx4 acc[8];

    #pragma unroll
    for (int layer = 0; layer < 2; layer++) {
        const unsigned short* Wh  = layer ? W2h : W1h;
        const unsigned short* Wlo = layer ? W2l : W1l;
        #pragma unroll
        for (int nf = 0; nf < 8; nf++) acc[nf] = (floatx4){0.f, 0.f, 0.f, 0.f};

        #pragma unroll
        for (int ks = 0; ks < 4; ks++) {
            short8 ah, al;
            if (layer == 0) {
                float f[8] = {0.f,0.f,0.f,0.f,0.f,0.f,0.f,0.f};
                if (rowok) {
                    float4 v0 = *(const float4*)(xe + e * 128 + ks * 32 + quad * 8);
                    float4 v1 = *(const float4*)(xe + e * 128 + ks * 32 + quad * 8 + 4);
                    f[0] = v0.x; f[1] = v0.y; f[2] = v0.z; f[3] = v0.w;
                    f[4] = v1.x; f[5] = v1.y; f[6] = v1.z; f[7] = v1.w;
                }
                #pragma unroll
                for (int j = 0; j < 8; j++) {
                    unsigned short h, l;
                    split_bf(f[j], h, l);
                    ah[j] = (short)h; al[j] = (short)l;
                }
            } else {
                ah = *(const short8*)&Ah[row_loc * 136 + ks * 32 + quad * 8];
                al = *(const short8*)&Al[row_loc * 136 + ks * 32 + quad * 8];
            }
            #pragma unroll
            for (int nf = 0; nf < 8; nf++) {
                size_t wo = (size_t)(nf * 16 + l15) * 128 + ks * 32 + quad * 8;
                short8 wh = *(const short8*)(Wh  + wo);
                short8 wl = *(const short8*)(Wlo + wo);
                acc[nf] = __builtin_amdgcn_mfma_f32_16x16x32_bf16(wh, ah, acc[nf], 0, 0, 0);
                acc[nf] = __builtin_amdgcn_mfma_f32_16x16x32_bf16(wh, al, acc[nf], 0, 0, 0);
                acc[nf] = __builtin_amdgcn_mfma_f32_16x16x32_bf16(wl, ah, acc[nf], 0, 0, 0);
            }
        }

        const float* bl  = layer ? b2  : b1;
        const float* gl  = layer ? g2  : g1;
        const float* bel = layer ? be2 : be1;

        float s = 0.f, q = 0.f;
        #pragma unroll
        for (int nf = 0; nf < 8; nf++) {
            float4 bb = *(const float4*)(bl + nf * 16 + quad * 4);
            acc[nf][0] += bb.x; acc[nf][1] += bb.y; acc[nf][2] += bb.z; acc[nf][3] += bb.w;
            #pragma unroll
            for (int r = 0; r < 4; r++) { s += acc[nf][r]; q += acc[nf][r] * acc[nf][r]; }
        }
        s += __shfl_xor(s, 16); s += __shfl_xor(s, 32);
        q += __shfl_xor(q, 16); q += __shfl_xor(q, 32);
        float mu  = s * (1.f / 128.f);
        float var = q * (1.f / 128.f) - mu * mu;
        float rs  = rsqrtf(var + 1e-6f);

        if (layer == 0) {
            #pragma unroll
            for (int nf = 0; nf < 8; nf++) {
                float4 gg  = *(const float4*)(gl  + nf * 16 + quad * 4);
                float4 bb2 = *(const float4*)(bel + nf * 16 + quad * 4);
                float vv[4];
                vv[0] = (acc[nf][0] - mu) * rs * gg.x + bb2.x;
                vv[1] = (acc[nf][1] - mu) * rs * gg.y + bb2.y;
                vv[2] = (acc[nf][2] - mu) * rs * gg.z + bb2.z;
                vv[3] = (acc[nf][3] - mu) * rs * gg.w + bb2.w;
                unsigned short h4[4], l4[4];
                #pragma unroll
                for (int r = 0; r < 4; r++) {
                    float v = vv[r];
                    v = v / (1.f + __expf(-v));       // silu
                    split_bf(v, h4[r], l4[r]);
                }
                *(uint2*)&Ah[row_loc * 136 + nf * 16 + quad * 4] =
                    make_uint2((unsigned)h4[0] | ((unsigned)h4[1] << 16),
                               (unsigned)h4[2] | ((unsigned)h4[3] << 16));
                *(uint2*)&Al[row_loc * 136 + nf * 16 + quad * 4] =
                    make_uint2((unsigned)l4[0] | ((unsigned)l4[1] << 16),
                               (unsigned)l4[2] | ((unsigned)l4[3] << 16));
            }
            __syncthreads();
        } else {
            if (rowok) {
                #pragma unroll
                for (int nf = 0; nf < 8; nf++) {
                    float4 gg  = *(const float4*)(gl  + nf * 16 + quad * 4);
                    float4 bb2 = *(const float4*)(bel + nf * 16 + quad * 4);
                    unsigned short p[4];
                    float vv[4];
                    vv[0] = (acc[nf][0] - mu) * rs * gg.x + bb2.x;
                    vv[1] = (acc[nf][1] - mu) * rs * gg.y + bb2.y;
                    vv[2] = (acc[nf][2] - mu) * rs * gg.z + bb2.z;
                    vv[3] = (acc[nf][3] - mu) * rs * gg.w + bb2.w;
                    #pragma unroll
                    for (int r = 0; r < 4; r++) {
                        float v = vv[r];
                        v = v / (1.f + __expf(-v));   // silu
                        p[r] = f2bf(v);
                    }
                    *(uint2*)(h2b + e * 128 + nf * 16 + quad * 4) =
                        make_uint2((unsigned)p[0] | ((unsigned)p[1] << 16),
                                   (unsigned)p[2] | ((unsigned)p[3] << 16));
                }
            }
        }
    }
}

// ---------------- W3 transpose prep: W3bT[n][k] = bf16(W3[k][n]), [640][128] ------------
__global__ __launch_bounds__(256) void w3t_kernel(const float* __restrict__ W3,
                                                  unsigned short* __restrict__ W3bT)
{
    int idx = blockIdx.x * 256 + threadIdx.x;   // 81920 total
    int n = idx >> 7, k = idx & 127;
    W3bT[idx] = f2bf(W3[(size_t)k * 640 + n]);
}

// ---------------- Layer 3 via MFMA: h3 = h2 @ W3 + b3, stored bf16 [E,640] --------------
__global__ __launch_bounds__(256) void gemm3_mfma_kernel(
    const unsigned short* __restrict__ h2b, const unsigned short* __restrict__ W3bT,
    const float* __restrict__ b3, unsigned short* __restrict__ h3b, int E)
{
    __shared__ unsigned short As[64 * 136];   // +8 bf16 pad

    int t    = threadIdx.x;
    int lane = t & 63;
    int w    = t >> 6;
    int mw   = w & 1, nw = w >> 1;
    int l15  = lane & 15, quad = lane >> 4;
    int e0   = blockIdx.x * 64;
    int n0   = blockIdx.y * 128;

    for (int p = 0; p < 4; p++) {
        int idx = p * 256 + t;
        int row = idx >> 4;
        int c16 = idx & 15;
        uint4 v = make_uint4(0, 0, 0, 0);
        if (e0 + row < E) v = *(const uint4*)(h2b + (size_t)(e0 + row) * 128 + c16 * 8);
        *(uint4*)&As[row * 136 + c16 * 8] = v;
    }

    short8 bfrag[4][4];
    {
        const unsigned short* bbase = W3bT + (size_t)(n0 + nw * 64) * 128;
        for (int ks = 0; ks < 4; ks++)
            for (int nf = 0; nf < 4; nf++)
                bfrag[ks][nf] = *(const short8*)(bbase + (size_t)(nf * 16 + l15) * 128 + ks * 32 + quad * 8);
    }

    floatx4 acc[2][4];
    for (int mf = 0; mf < 2; mf++)
        for (int nf = 0; nf < 4; nf++)
            acc[mf][nf] = (floatx4){0.f, 0.f, 0.f, 0.f};

    __syncthreads();

    for (int ks = 0; ks < 4; ks++) {
        short8 afrag[2];
        for (int mf = 0; mf < 2; mf++)
            afrag[mf] = *(const short8*)&As[(mw * 32 + mf * 16 + l15) * 136 + ks * 32 + quad * 8];
        for (int mf = 0; mf < 2; mf++)
            for (int nf = 0; nf < 4; nf++)
                acc[mf][nf] = __builtin_amdgcn_mfma_f32_16x16x32_bf16(
                    bfrag[ks][nf], afrag[mf], acc[mf][nf], 0, 0, 0);
    }

    for (int nf = 0; nf < 4; nf++) {
        float4 bias = *(const float4*)&b3[n0 + nw * 64 + nf * 16 + quad * 4];
        for (int mf = 0; mf < 2; mf++) {
            int m = e0 + mw * 32 + mf * 16 + l15;
            if (m < E) {
                floatx4 v = acc[mf][nf];
                unsigned lo = (unsigned)f2bf(v[0] + bias.x) | ((unsigned)f2bf(v[1] + bias.y) << 16);
                unsigned hi = (unsigned)f2bf(v[2] + bias.z) | ((unsigned)f2bf(v[3] + bias.w) << 16);
                *(uint2*)(h3b + (size_t)m * 640 + n0 + nw * 64 + nf * 16 + quad * 4) = make_uint2(lo, hi);
            }
        }
    }
}

// ---------------- CSR build ---------------------------------------------------------
__global__ void hist_kernel(const int* __restrict__ ei, const int* __restrict__ noff,
                            int* __restrict__ counts, int E)
{
    int i = blockIdx.x * blockDim.x + threadIdx.x;
    if (i < E) {
        int tgt = ei[E + i] - noff[0];
        atomicAdd(&counts[tgt], 1);
    }
}

__global__ __launch_bounds__(1024) void scan_kernel(const int* __restrict__ counts,
                                                    int* __restrict__ offsets,
                                                    int* __restrict__ cursor, int N)
{
    __shared__ int part[1024];
    int t = threadIdx.x;
    int per = (N + 1023) / 1024;
    int beg = t * per;
    int end = beg + per; if (end > N) end = N; if (beg > N) beg = N;
    int s = 0;
    for (int i = beg; i < end; i++) s += counts[i];
    part[t] = s;
    __syncthreads();
    for (int off = 1; off < 1024; off <<= 1) {
        int v = part[t];
        int u = (t >= off) ? part[t - off] : 0;
        __syncthreads();
        part[t] = v + u;
        __syncthreads();
    }
    int run = (t == 0) ? 0 : part[t - 1];
    for (int i = beg; i < end; i++) {
        offsets[i] = run;
        cursor[i]  = run;
        run += counts[i];
    }
    if (t == 1023) offsets[N] = part[1023];
}

__global__ void scatter_kernel(const int* __restrict__ ei, const int* __restrict__ noff,
                               int* __restrict__ cursor, int* __restrict__ edge_ids, int E)
{
    int i = blockIdx.x * blockDim.x + threadIdx.x;
    if (i < E) {
        int tgt = ei[E + i] - noff[0];
        int pos = atomicAdd(&cursor[tgt], 1);
        edge_ids[pos] = i;
    }
}

// ---------------- Gather via MFMA: out[n] = x[n] + sum_e (env_e/16)*wig_e[:,:5] @ h3_e --
// Per node: A = wig (25 x 5d, env/16 folded, hi/lo bf16 split), B = h3 (5d x 128, bf16).
// K padded to 8 slots/edge -> one K=32 MFMA chunk = 4 edges, lane k-offset quad*8+jj
// maps to (edge=quad, kslot=jj). Block = 1 node, 4 waves; wave w owns c in [w*32,w*32+32).
// D layout (mirrors gemm3's verified mapping): first operand (h3, rows=c) -> rows
// quad*4+r; second operand (wig, rows=j) -> cols l15. Epilogue: float4 stores.
__global__ __launch_bounds__(256) void gather_mfma_kernel(
    const float* __restrict__ x, const unsigned short* __restrict__ h3b,
    const float* __restrict__ wig, const float* __restrict__ env,
    const int* __restrict__ offsets, const int* __restrict__ edge_ids,
    float* __restrict__ out, int N)
{
    __shared__ unsigned short Bs[2][4 * 648];   // [buf][e*648 + k*128 + c], +8 pad/edge
    __shared__ unsigned short Ah[2][32 * 40];   // [buf][j*40 + e*8 + k]  (hi)
    __shared__ unsigned short Al[2][32 * 40];   // (lo)

    int n = blockIdx.x;
    int t = threadIdx.x;
    int lane = t & 63, w = t >> 6;
    int l15 = lane & 15, quad = lane >> 4;

    int beg = offsets[n], end = offsets[n + 1];
    int d = end - beg;
    int nchunk = (d + 3) >> 2;

    // zero-init A (both bufs, hi+lo): covers pad kslots 5..7 and rows j>=25 forever
    {
        unsigned* ph = (unsigned*)Ah;
        unsigned* pl = (unsigned*)Al;
        for (int idx = t; idx < 1280; idx += 256) { ph[idx] = 0u; pl[idx] = 0u; }
    }

    // hoist x loads
    float4 xr[2][2];
    #pragma unroll
    for (int nf = 0; nf < 2; nf++)
        #pragma unroll
        for (int mf = 0; mf < 2; mf++) {
            int j = mf * 16 + l15;
            int c = w * 32 + nf * 16 + quad * 4;
            xr[nf][mf] = (j < 25) ? *(const float4*)(x + (size_t)n * 3200 + j * 128 + c)
                                  : make_float4(0.f, 0.f, 0.f, 0.f);
        }

    floatx4 acc[2][2];
    #pragma unroll
    for (int nf = 0; nf < 2; nf++)
        #pragma unroll
        for (int mf = 0; mf < 2; mf++)
            acc[nf][mf] = (floatx4){0.f, 0.f, 0.f, 0.f};

    auto stage_load = [&](int ci, uint4& a0, uint4& a1, float& wv0, float& wv1) {
        {   // h3 part: 320 uint4 chunks (4 edges x 80)
            int el = t / 80, off = t % 80;
            int ge = ci * 4 + el;
            if (ge < d) {
                int eid = edge_ids[beg + ge];
                a0 = *(const uint4*)(h3b + (size_t)eid * 640 + off * 8);
            }
        }
        if (t < 64) {
            int idx1 = 256 + t;
            int el = idx1 / 80, off = idx1 % 80;
            int ge = ci * 4 + el;
            if (ge < d) {
                int eid = edge_ids[beg + ge];
                a1 = *(const uint4*)(h3b + (size_t)eid * 640 + off * 8);
            }
        }
        {   // wig part: 500 slots (4 x 25 x 5)
            int el = t / 125, r = t % 125;
            int ge = ci * 4 + el;
            wv0 = 0.f;
            if (ge < d) {
                int eid = edge_ids[beg + ge];
                int j = r / 5, k = r - j * 5;
                wv0 = wig[(size_t)eid * 475 + j * 19 + k] * env[eid] * 0.0625f;
            }
        }
        wv1 = 0.f;
        if (t < 244) {
            int idx = t + 256;
            int el = idx / 125, r = idx % 125;
            int ge = ci * 4 + el;
            if (ge < d) {
                int eid = edge_ids[beg + ge];
                int j = r / 5, k = r - j * 5;
                wv1 = wig[(size_t)eid * 475 + j * 19 + k] * env[eid] * 0.0625f;
            }
        }
    };

    auto stage_write = [&](int buf, const uint4& a0, const uint4& a1, float wv0, float wv1) {
        {
            int el = t / 80, off = t % 80;
            *(uint4*)&Bs[buf][el * 648 + off * 8] = a0;
        }
        if (t < 64) {
            int idx1 = 256 + t;
            int el = idx1 / 80, off = idx1 % 80;
            *(uint4*)&Bs[buf][el * 648 + off * 8] = a1;
        }
        {
            int el = t / 125, r = t % 125;
            int j = r / 5, k = r - j * 5;
            unsigned short h, l; split_bf(wv0, h, l);
            Ah[buf][j * 40 + el * 8 + k] = h;
            Al[buf][j * 40 + el * 8 + k] = l;
        }
        if (t < 244) {
            int idx = t + 256;
            int el = idx / 125, r = idx % 125;
            int j = r / 5, k = r - j * 5;
            unsigned short h, l; split_bf(wv1, h, l);
            Ah[buf][j * 40 + el * 8 + k] = h;
            Al[buf][j * 40 + el * 8 + k] = l;
        }
    };

    uint4 a0 = make_uint4(0,0,0,0), a1 = make_uint4(0,0,0,0);
    float wv0 = 0.f, wv1 = 0.f;
    if (nchunk > 0) stage_load(0, a0, a1, wv0, wv1);
    __syncthreads();                       // zero-init visible
    if (nchunk > 0) stage_write(0, a0, a1, wv0, wv1);
    __syncthreads();

    for (int ci = 0; ci < nchunk; ci++) {
        int cur = ci & 1;
        bool hn = (ci + 1) < nchunk;
        uint4 b0 = make_uint4(0,0,0,0), b1 = make_uint4(0,0,0,0);
        float u0 = 0.f, u1 = 0.f;
        if (hn) stage_load(ci + 1, b0, b1, u0, u1);

        int nvalid = d - ci * 4; if (nvalid > 4) nvalid = 4;

        short8 ah0 = *(const short8*)&Ah[cur][(l15) * 40 + quad * 8];
        short8 ah1 = *(const short8*)&Ah[cur][(16 + l15) * 40 + quad * 8];
        short8 al0 = *(const short8*)&Al[cur][(l15) * 40 + quad * 8];
        short8 al1 = *(const short8*)&Al[cur][(16 + l15) * 40 + quad * 8];

        #pragma unroll
        for (int nf = 0; nf < 2; nf++) {
            int c = w * 32 + nf * 16 + l15;
            short8 b = (short8){0,0,0,0,0,0,0,0};
            if (quad < nvalid) {
                const unsigned short* bp = &Bs[cur][quad * 648 + c];
                b[0] = (short)bp[0];   b[1] = (short)bp[128]; b[2] = (short)bp[256];
                b[3] = (short)bp[384]; b[4] = (short)bp[512];
            }
            acc[nf][0] = __builtin_amdgcn_mfma_f32_16x16x32_bf16(b, ah0, acc[nf][0], 0, 0, 0);
            acc[nf][0] = __builtin_amdgcn_mfma_f32_16x16x32_bf16(b, al0, acc[nf][0], 0, 0, 0);
            acc[nf][1] = __builtin_amdgcn_mfma_f32_16x16x32_bf16(b, ah1, acc[nf][1], 0, 0, 0);
            acc[nf][1] = __builtin_amdgcn_mfma_f32_16x16x32_bf16(b, al1, acc[nf][1], 0, 0, 0);
        }

        if (hn) stage_write(cur ^ 1, b0, b1, u0, u1);
        __syncthreads();
    }

    // epilogue: out = x + acc (env & 1/16 already folded into wig)
    #pragma unroll
    for (int nf = 0; nf < 2; nf++)
        #pragma unroll
        for (int mf = 0; mf < 2; mf++) {
            int j = mf * 16 + l15;
            if (j < 25) {
                int c = w * 32 + nf * 16 + quad * 4;
                float4 o;
                o.x = xr[nf][mf].x + acc[nf][mf][0];
                o.y = xr[nf][mf].y + acc[nf][mf][1];
                o.z = xr[nf][mf].z + acc[nf][mf][2];
                o.w = xr[nf][mf].w + acc[nf][mf][3];
                *(float4*)(out + (size_t)n * 3200 + j * 128 + c) = o;
            }
        }
}

extern "C" void kernel_launch(void* const* d_in, const int* in_sizes, int n_in,
                              void* d_out, int out_size, void* d_ws, size_t ws_size,
                              hipStream_t stream) {
    const float* x          = (const float*)d_in[0];
    const float* x_edge     = (const float*)d_in[1];
    const int*   edge_index = (const int*)d_in[2];
    const float* wigner     = (const float*)d_in[3];
    const float* envel      = (const float*)d_in[4];
    const int*   node_off   = (const int*)d_in[5];
    const float* W1 = (const float*)d_in[6];
    const float* b1 = (const float*)d_in[7];
    const float* g1 = (const float*)d_in[8];
    const float* be1 = (const float*)d_in[9];
    const float* W2 = (const float*)d_in[10];
    const float* b2 = (const float*)d_in[11];
    const float* g2 = (const float*)d_in[12];
    const float* be2 = (const float*)d_in[13];
    const float* W3 = (const float*)d_in[14];
    const float* b3 = (const float*)d_in[15];
    float* out = (float*)d_out;

    int E = in_sizes[1] / 128;    // 100000
    int N = in_sizes[0] / 3200;   // 6250

    // workspace layout
    char* w = (char*)d_ws;
    unsigned short* h2b  = (unsigned short*)w; w += (size_t)E * 128 * sizeof(unsigned short);
    unsigned short* h3b  = (unsigned short*)w; w += (size_t)E * 640 * sizeof(unsigned short);
    unsigned short* W3bT = (unsigned short*)w; w += (size_t)640 * 128 * sizeof(unsigned short);
    unsigned short* W1h  = (unsigned short*)w; w += (size_t)128 * 128 * sizeof(unsigned short);
    unsigned short* W1l  = (unsigned short*)w; w += (size_t)128 * 128 * sizeof(unsigned short);
    unsigned short* W2h  = (unsigned short*)w; w += (size_t)128 * 128 * sizeof(unsigned short);
    unsigned short* W2l  = (unsigned short*)w; w += (size_t)128 * 128 * sizeof(unsigned short);
    int* counts   = (int*)w;            w += (size_t)((N + 63) & ~63) * sizeof(int);
    int* offsets  = (int*)w;            w += (size_t)((N + 1 + 63) & ~63) * sizeof(int);
    int* cursor   = (int*)w;            w += (size_t)((N + 63) & ~63) * sizeof(int);
    int* edge_ids = (int*)w;            w += (size_t)E * sizeof(int);

    hipMemsetAsync(counts, 0, (size_t)N * sizeof(int), stream);

    dim3 blk(256);
    w12t_kernel<<<dim3(128), blk, 0, stream>>>(W1, W2, W1h, W1l, W2h, W2l);

    mlp12_kernel<<<dim3((E + 63) / 64), blk, 0, stream>>>(
        x_edge, W1h, W1l, b1, g1, be1, W2h, W2l, b2, g2, be2, h2b, E);

    w3t_kernel<<<dim3(320), blk, 0, stream>>>(W3, W3bT);

    hist_kernel<<<dim3((E + 255) / 256), blk, 0, stream>>>(edge_index, node_off, counts, E);
    scan_kernel<<<dim3(1), dim3(1024), 0, stream>>>(counts, offsets, cursor, N);
    scatter_kernel<<<dim3((E + 255) / 256), blk, 0, stream>>>(edge_index, node_off, cursor, edge_ids, E);

    gemm3_mfma_kernel<<<dim3((E + 63) / 64, 5), blk, 0, stream>>>(h2b, W3bT, b3, h3b, E);

    gather_mfma_kernel<<<dim3(N), blk, 0, stream>>>(x, h3b, wigner, envel, offsets, edge_ids, out, N);
}